// Round 1
// baseline (147.331 us; speedup 1.0000x reference)
//
#include <hip/hip_runtime.h>

#define NN 256   // nodes per graph
#define DM 128   // gcn hidden dim
#define NH 4     // heads
#define DVV 64   // d_kv
#define LK 72    // row stride (elems) for ks/qs/RsT
#define LT 264   // row stride for vsT/Os/Ps
#define LX 136   // row stride for staged x

typedef __bf16 bf16;
typedef __attribute__((ext_vector_type(8))) __bf16 bf16x8;
typedef __attribute__((ext_vector_type(4))) float f32x4;

static __device__ __forceinline__ unsigned short f2b(float f) {
  return __builtin_bit_cast(unsigned short, (__bf16)f);
}
static __device__ __forceinline__ bf16x8 ldf(const unsigned short* p) {
  return *(const bf16x8*)p;
}

#define MFMA16(a, b, c) __builtin_amdgcn_mfma_f32_16x16x32_bf16((a), (b), (c), 0, 0, 0)

__global__ __launch_bounds__(256, 1)
void vlrgat_kernel(const float* __restrict__ gnn,
                   const float* __restrict__ Wq, const float* __restrict__ Wk,
                   const float* __restrict__ Wv, const float* __restrict__ Wfc,
                   const float* __restrict__ ln1g, const float* __restrict__ ln1b,
                   const float* __restrict__ ln2g, const float* __restrict__ ln2b,
                   float* __restrict__ out)
{
  // 153 KB total LDS
  __shared__ __align__(16) unsigned short ks [NN  * LK];  // K   [256][72]
  __shared__ __align__(16) unsigned short vsT[DVV * LT];  // V^T [64][264] cols=n
  __shared__ __align__(16) unsigned short Os [DVV * LT];  // O concat [64][264]
  __shared__ __align__(16) unsigned short qs [64  * LK];  // q block [64][72]
  __shared__ __align__(16) unsigned short RsT[64  * LK];  // R^T [64 e][72 n]
  __shared__ __align__(16) unsigned short U  [DVV * LT];  // xs [64][136] | Ps [64][264]

  unsigned short* const xs = U;
  unsigned short* const Ps = U;

  const int t  = threadIdx.x;
  const int w  = t >> 6;    // wave 0..3
  const int l  = t & 63;
  const int lr = l & 15;
  const int lg = l >> 4;    // 0..3
  const int cb = blockIdx.x;
  const float* const xg = gnn + (size_t)cb * NN * DM;   // x[cb] = gnn viewed [256][256][128]

  // stage 64 rows of x (r0..r0+63) -> xs bf16; wave w stages exactly its rows [16w,16w+16)
  auto stage_x = [&](int r0) {
    const int row = t >> 2;          // 0..63
    const int c0  = (t & 3) * 32;
    const float4* src = (const float4*)(xg + (size_t)(r0 + row) * DM + c0);
    unsigned short* dst = &xs[row * LX + c0];
#pragma unroll
    for (int i = 0; i < 8; ++i) {
      float4 f = src[i];
      dst[4*i+0] = f2b(f.x);
      dst[4*i+1] = f2b(f.y);
      dst[4*i+2] = f2b(f.z);
      dst[4*i+3] = f2b(f.w);
    }
  };

  // B-fragment gather from a row-major global fp32 weight: elem j -> W[(k0+j)*ld + col]
  auto wfrag = [&](const float* __restrict__ W, int ld, int k0, int col) -> bf16x8 {
    bf16x8 r;
#pragma unroll
    for (int j = 0; j < 8; ++j) r[j] = (bf16)W[(size_t)(k0 + j) * ld + col];
    return r;
  };

  for (int h = 0; h < NH; ++h) {
    __syncthreads();   // ks/vsT (and U) about to be overwritten vs prior head's readers

    // ---------------- K,V projection: [256,128] @ [128,64] x2 ----------------
    {
      bf16x8 bk[4][4], bv[4][4];
#pragma unroll
      for (int ct = 0; ct < 4; ++ct)
#pragma unroll
        for (int kt = 0; kt < 4; ++kt) {
          const int col = h * DVV + ct * 16 + lr;
          const int k0  = kt * 32 + lg * 8;
          bk[ct][kt] = wfrag(Wk, 256, k0, col);
          bv[ct][kt] = wfrag(Wv, 256, k0, col);
        }
      for (int cc = 0; cc < 4; ++cc) {
        stage_x(cc * 64);      // wave-local rows; no barrier needed
        bf16x8 xa[4];
#pragma unroll
        for (int kt = 0; kt < 4; ++kt)
          xa[kt] = ldf(&xs[(w*16 + lr) * LX + kt*32 + lg*8]);
#pragma unroll
        for (int ct = 0; ct < 4; ++ct) {
          f32x4 ak = {0.f,0.f,0.f,0.f};
          f32x4 av = {0.f,0.f,0.f,0.f};
#pragma unroll
          for (int kt = 0; kt < 4; ++kt) {
            ak = MFMA16(xa[kt], bk[ct][kt], ak);
            av = MFMA16(xa[kt], bv[ct][kt], av);
          }
#pragma unroll
          for (int r = 0; r < 4; ++r) {
            const int n = cc*64 + w*16 + lg*4 + r;
            ks [n * LK + ct*16 + lr]   = f2b(ak[r]);
            vsT[(ct*16 + lr) * LT + n] = f2b(av[r]);
          }
        }
      }
    }

    bf16x8 bq[4][4];
#pragma unroll
    for (int ct = 0; ct < 4; ++ct)
#pragma unroll
      for (int kt = 0; kt < 4; ++kt)
        bq[ct][kt] = wfrag(Wq, 256, kt*32 + lg*8, h*DVV + ct*16 + lr);

    f32x4 oacc[4];
#pragma unroll
    for (int ct = 0; ct < 4; ++ct) oacc[ct] = (f32x4){0.f,0.f,0.f,0.f};

    __syncthreads();   // K/V published to all waves

    // ---------------- attention, 64 query rows per block-iteration ----------------
    for (int qb = 0; qb < 4; ++qb) {
      stage_x(qb * 64);                    // wave-local rows of U
      {
        bf16x8 xa[4];
#pragma unroll
        for (int kt = 0; kt < 4; ++kt)
          xa[kt] = ldf(&xs[(w*16 + lr) * LX + kt*32 + lg*8]);
#pragma unroll
        for (int ct = 0; ct < 4; ++ct) {
          f32x4 aq = {0.f,0.f,0.f,0.f};
#pragma unroll
          for (int kt = 0; kt < 4; ++kt)
            aq = MFMA16(xa[kt], bq[ct][kt], aq);
#pragma unroll
          for (int r = 0; r < 4; ++r)
            qs[(w*16 + lg*4 + r) * LK + ct*16 + lr] = f2b(aq[r] * 0.125f); // /sqrt(64)
        }
      }
      __syncthreads();  // all waves done reading xs before Ps (same region) is written

      // S = q @ K^T : wave owns 16 query rows x 256 keys
      f32x4 sa[16];
      {
        bf16x8 qa[2];
#pragma unroll
        for (int kt = 0; kt < 2; ++kt)
          qa[kt] = ldf(&qs[(w*16 + lr) * LK + kt*32 + lg*8]);
#pragma unroll
        for (int ck = 0; ck < 16; ++ck) {
          f32x4 a = {0.f,0.f,0.f,0.f};
#pragma unroll
          for (int kt = 0; kt < 2; ++kt)
            a = MFMA16(qa[kt], ldf(&ks[(ck*16 + lr) * LK + kt*32 + lg*8]), a);
          sa[ck] = a;
        }
      }
      // row softmax: per-lane over 16 col-tiles, then 16-lane shfl reduction
      float inv[4];
#pragma unroll
      for (int r = 0; r < 4; ++r) {
        float m = sa[0][r];
#pragma unroll
        for (int ck = 1; ck < 16; ++ck) m = fmaxf(m, sa[ck][r]);
        m = fmaxf(m, __shfl_xor(m, 1));
        m = fmaxf(m, __shfl_xor(m, 2));
        m = fmaxf(m, __shfl_xor(m, 4));
        m = fmaxf(m, __shfl_xor(m, 8));
        float s = 0.f;
#pragma unroll
        for (int ck = 0; ck < 16; ++ck) {
          float e = __expf(sa[ck][r] - m);
          sa[ck][r] = e;
          s += e;
        }
        s += __shfl_xor(s, 1);
        s += __shfl_xor(s, 2);
        s += __shfl_xor(s, 4);
        s += __shfl_xor(s, 8);
        inv[r] = 1.0f / s;
      }
#pragma unroll
      for (int ck = 0; ck < 16; ++ck)
#pragma unroll
        for (int r = 0; r < 4; ++r)
          Ps[(w*16 + lg*4 + r) * LT + ck*16 + lr] = f2b(sa[ck][r] * inv[r]);

      // R = P @ V  (own P rows, full V) -> stored transposed
      {
        bf16x8 pa[8];
#pragma unroll
        for (int kt = 0; kt < 8; ++kt)
          pa[kt] = ldf(&Ps[(w*16 + lr) * LT + kt*32 + lg*8]);
#pragma unroll
        for (int ct = 0; ct < 4; ++ct) {
          f32x4 a = {0.f,0.f,0.f,0.f};
#pragma unroll
          for (int kt = 0; kt < 8; ++kt)
            a = MFMA16(pa[kt], ldf(&vsT[(ct*16 + lr) * LT + kt*32 + lg*8]), a);
#pragma unroll
          for (int r = 0; r < 4; ++r)
            RsT[(ct*16 + lr) * LK + w*16 + lg*4 + r] = f2b(a[r]);
        }
      }
      __syncthreads();  // RsT consumed cross-wave

      // O += V_blk^T @ R_blk   (d rows 16w..16w+15 per wave, accumulated over qb)
#pragma unroll
      for (int kt = 0; kt < 2; ++kt) {
        bf16x8 va = ldf(&vsT[(w*16 + lr) * LT + qb*64 + kt*32 + lg*8]);
#pragma unroll
        for (int ct = 0; ct < 4; ++ct)
          oacc[ct] = MFMA16(va, ldf(&RsT[(ct*16 + lr) * LK + kt*32 + lg*8]), oacc[ct]);
      }
      __syncthreads();  // O reads done before next qb rewrites RsT / U
    }

    // publish this head's O slice (wave-local rows)
#pragma unroll
    for (int ct = 0; ct < 4; ++ct)
#pragma unroll
      for (int r = 0; r < 4; ++r)
        Os[(w*16 + lg*4 + r) * LT + h*DVV + ct*16 + lr] = f2b(oacc[ct][r]);
  }

  // ---------------- epilogue: F = Os @ Wfc, then double LayerNorm ----------------
  bf16x8 oa[8];
#pragma unroll
  for (int kt = 0; kt < 8; ++kt)
    oa[kt] = ldf(&Os[(w*16 + lr) * LT + kt*32 + lg*8]);
  f32x4 fa[4];
#pragma unroll
  for (int ct = 0; ct < 4; ++ct) {
    f32x4 a = {0.f,0.f,0.f,0.f};
#pragma unroll
    for (int kt = 0; kt < 8; ++kt)
      a = MFMA16(oa[kt], wfrag(Wfc, DVV, kt*32 + lg*8, ct*16 + lr), a);
    fa[ct] = a;
  }

  float g1v[4], b1v[4], g2v[4], b2v[4];
#pragma unroll
  for (int ct = 0; ct < 4; ++ct) {
    g1v[ct] = ln1g[ct*16 + lr];
    b1v[ct] = ln1b[ct*16 + lr];
    g2v[ct] = ln2g[ct*16 + lr];
    b2v[ct] = ln2b[ct*16 + lr];
  }
  const int bb = cb & 31;        // graph index b  (cb = c*32 + b)
  const int ch = cb >> 5;        // channel index c
  float* const obase = out + (size_t)(bb*8 + ch) * 64 * 64;
#pragma unroll
  for (int r = 0; r < 4; ++r) {
    const int row = w*16 + lg*4 + r;
    float x0 = fa[0][r], x1 = fa[1][r], x2 = fa[2][r], x3 = fa[3][r];
    float mu = x0 + x1 + x2 + x3;
    mu += __shfl_xor(mu, 1); mu += __shfl_xor(mu, 2);
    mu += __shfl_xor(mu, 4); mu += __shfl_xor(mu, 8);
    mu *= 0.015625f;
    float d0 = x0-mu, d1 = x1-mu, d2 = x2-mu, d3 = x3-mu;
    float vr = d0*d0 + d1*d1 + d2*d2 + d3*d3;
    vr += __shfl_xor(vr, 1); vr += __shfl_xor(vr, 2);
    vr += __shfl_xor(vr, 4); vr += __shfl_xor(vr, 8);
    const float is1 = rsqrtf(vr * 0.015625f + 1e-6f);
    float y0 = d0*is1*g1v[0] + b1v[0];
    float y1 = d1*is1*g1v[1] + b1v[1];
    float y2 = d2*is1*g1v[2] + b1v[2];
    float y3 = d3*is1*g1v[3] + b1v[3];
    float mu2 = y0 + y1 + y2 + y3;
    mu2 += __shfl_xor(mu2, 1); mu2 += __shfl_xor(mu2, 2);
    mu2 += __shfl_xor(mu2, 4); mu2 += __shfl_xor(mu2, 8);
    mu2 *= 0.015625f;
    float e0 = y0-mu2, e1 = y1-mu2, e2 = y2-mu2, e3 = y3-mu2;
    float v2 = e0*e0 + e1*e1 + e2*e2 + e3*e3;
    v2 += __shfl_xor(v2, 1); v2 += __shfl_xor(v2, 2);
    v2 += __shfl_xor(v2, 4); v2 += __shfl_xor(v2, 8);
    const float is2 = rsqrtf(v2 * 0.015625f + 1e-6f);
    float* const op = obase + (size_t)row * 64;
    op[ 0 + lr] = e0*is2*g2v[0] + b2v[0];
    op[16 + lr] = e1*is2*g2v[1] + b2v[1];
    op[32 + lr] = e2*is2*g2v[2] + b2v[2];
    op[48 + lr] = e3*is2*g2v[3] + b2v[3];
  }
}

extern "C" void kernel_launch(void* const* d_in, const int* in_sizes, int n_in,
                              void* d_out, int out_size, void* d_ws, size_t ws_size,
                              hipStream_t stream) {
  const float* gnn = (const float*)d_in[0];
  const float* Wq  = (const float*)d_in[1];
  const float* Wk  = (const float*)d_in[2];
  const float* Wv  = (const float*)d_in[3];
  const float* Wfc = (const float*)d_in[4];
  const float* l1g = (const float*)d_in[5];
  const float* l1b = (const float*)d_in[6];
  const float* l2g = (const float*)d_in[7];
  const float* l2b = (const float*)d_in[8];
  (void)in_sizes; (void)n_in; (void)d_ws; (void)ws_size; (void)out_size;
  vlrgat_kernel<<<dim3(256), dim3(256), 0, stream>>>(
      gnn, Wq, Wk, Wv, Wfc, l1g, l1b, l2g, l2b, (float*)d_out);
}

// Round 2
// 112.212 us; speedup vs baseline: 1.3130x; 1.3130x over previous
//
#include <hip/hip_runtime.h>

#define NN 256   // nodes per graph
#define DM 128   // gcn hidden dim
#define NH 4     // heads
#define LK 72    // row stride (elems) for ks/qs/RsT
#define LT 264   // row stride for vsT/Os/Ps
#define LX 136   // row stride for staged x

typedef __bf16 bf16;
typedef __attribute__((ext_vector_type(8))) __bf16 bf16x8;
typedef __attribute__((ext_vector_type(4))) float f32x4;

static __device__ __forceinline__ unsigned short f2b(float f) {
  return __builtin_bit_cast(unsigned short, (__bf16)f);
}
static __device__ __forceinline__ bf16x8 ldf(const unsigned short* p) {
  return *(const bf16x8*)p;
}

#define MFMA16(a, b, c) __builtin_amdgcn_mfma_f32_16x16x32_bf16((a), (b), (c), 0, 0, 0)

__global__ __launch_bounds__(512, 1)
void vlrgat_kernel(const float* __restrict__ gnn,
                   const float* __restrict__ Wq, const float* __restrict__ Wk,
                   const float* __restrict__ Wv, const float* __restrict__ Wfc,
                   const float* __restrict__ ln1g, const float* __restrict__ ln1b,
                   const float* __restrict__ ln2g, const float* __restrict__ ln2b,
                   float* __restrict__ out)
{
  __shared__ __align__(16) unsigned short ks [NN * LK];     // K   [256][72]
  __shared__ __align__(16) unsigned short vsT[64 * LT];     // V^T [64][264] cols=n
  __shared__ __align__(16) unsigned short Os [64 * LT];     // O concat [64][264]
  __shared__ __align__(16) unsigned short qs [64 * LK];     // q block [64][72]
  __shared__ __align__(16) unsigned short RsT[64 * LK];     // R^T [64 e][72 q]
  __shared__ __align__(16) unsigned short U  [2 * 64 * LX]; // xs dbuf [2][64][136] | Ps [64][264]
  __shared__ __align__(16) float2 sm[64][2];                // per-row (max, sum) per key-half

  unsigned short* const Ps = U;

  const int t  = threadIdx.x;
  const int w  = t >> 6;     // wave 0..7
  const int l  = t & 63;
  const int lr = l & 15;
  const int lg = l >> 4;     // 0..3
  const int g  = w & 3;      // row-group 0..3
  const int hf = w >> 2;     // half 0..1 (splits ct / ck)
  const int cb = blockIdx.x;
  const float* const xg = gnn + (size_t)cb * NN * DM;

  // stage 64 rows of x -> U[buf] as bf16, all 512 threads, fully coalesced
  auto stage_x = [&](int r0, int buf) {
    const int row = t >> 3;           // 0..63
    const int c   = t & 7;            // float4 lane within row
    const float4* src = (const float4*)(xg + (size_t)(r0 + row) * DM) + c;
    unsigned short* dst = &U[buf * 64 * LX + row * LX + c * 4];
#pragma unroll
    for (int i = 0; i < 4; ++i) {
      float4 f = src[8 * i];
      unsigned short* d = dst + 32 * i;
      d[0] = f2b(f.x); d[1] = f2b(f.y); d[2] = f2b(f.z); d[3] = f2b(f.w);
    }
  };

  // B-fragment gather from row-major global fp32 weight: elem j -> W[(k0+j)*ld + col]
  auto wfrag = [&](const float* __restrict__ W, int ld, int k0, int col) -> bf16x8 {
    bf16x8 r;
#pragma unroll
    for (int j = 0; j < 8; ++j) r[j] = (bf16)W[(size_t)(k0 + j) * ld + col];
    return r;
  };

  for (int h = 0; h < NH; ++h) {
    __syncthreads();   // ks/vsT/U rewrite vs prior head's readers

    // ---------------- K,V projection (wave pair splits ct) ----------------
    {
      bf16x8 bk[2][4], bv[2][4];
#pragma unroll
      for (int c = 0; c < 2; ++c)
#pragma unroll
        for (int kt = 0; kt < 4; ++kt) {
          const int col = h * 64 + (hf * 2 + c) * 16 + lr;
          const int k0  = kt * 32 + lg * 8;
          bk[c][kt] = wfrag(Wk, 256, k0, col);
          bv[c][kt] = wfrag(Wv, 256, k0, col);
        }
      for (int cc = 0; cc < 4; ++cc) {
        stage_x(cc * 64, cc & 1);
        __syncthreads();            // stage visible to all waves
        bf16x8 xa[4];
#pragma unroll
        for (int kt = 0; kt < 4; ++kt)
          xa[kt] = ldf(&U[(cc & 1) * 64 * LX + (g * 16 + lr) * LX + kt * 32 + lg * 8]);
#pragma unroll
        for (int c = 0; c < 2; ++c) {
          f32x4 ak = {0.f, 0.f, 0.f, 0.f};
          f32x4 av = {0.f, 0.f, 0.f, 0.f};
#pragma unroll
          for (int kt = 0; kt < 4; ++kt) {
            ak = MFMA16(xa[kt], bk[c][kt], ak);
            av = MFMA16(xa[kt], bv[c][kt], av);
          }
          const int e = (hf * 2 + c) * 16 + lr;
#pragma unroll
          for (int r = 0; r < 4; ++r) {
            const int n = cc * 64 + g * 16 + lg * 4 + r;
            ks [n * LK + e]  = f2b(ak[r]);
            vsT[e * LT + n]  = f2b(av[r]);
          }
        }
      }
    }

    bf16x8 bq[2][4];
#pragma unroll
    for (int c = 0; c < 2; ++c)
#pragma unroll
      for (int kt = 0; kt < 4; ++kt)
        bq[c][kt] = wfrag(Wq, 256, kt * 32 + lg * 8, h * 64 + (hf * 2 + c) * 16 + lr);

    f32x4 oacc[2];
    oacc[0] = (f32x4){0.f, 0.f, 0.f, 0.f};
    oacc[1] = (f32x4){0.f, 0.f, 0.f, 0.f};

    __syncthreads();   // K/V published

    // ---------------- attention: 4 tiles of 64 query rows ----------------
    for (int qb = 0; qb < 4; ++qb) {
      stage_x(qb * 64, qb & 1);
      __syncthreads();            // stage visible (prior-iter hazards covered below)

      // Q projection (wave pair splits ct)
      {
        bf16x8 xa[4];
#pragma unroll
        for (int kt = 0; kt < 4; ++kt)
          xa[kt] = ldf(&U[(qb & 1) * 64 * LX + (g * 16 + lr) * LX + kt * 32 + lg * 8]);
#pragma unroll
        for (int c = 0; c < 2; ++c) {
          f32x4 aq = {0.f, 0.f, 0.f, 0.f};
#pragma unroll
          for (int kt = 0; kt < 4; ++kt)
            aq = MFMA16(xa[kt], bq[c][kt], aq);
#pragma unroll
          for (int r = 0; r < 4; ++r)
            qs[(g * 16 + lg * 4 + r) * LK + (hf * 2 + c) * 16 + lr] = f2b(aq[r] * 0.125f);
        }
      }
      __syncthreads();  // qs ready; xs reads done (Ps region may be written later)

      // S = q @ K^T : wave owns 16 q-rows x 128 keys (its half)
      f32x4 sa[8];
      {
        bf16x8 qa[2];
#pragma unroll
        for (int kt = 0; kt < 2; ++kt)
          qa[kt] = ldf(&qs[(g * 16 + lr) * LK + kt * 32 + lg * 8]);
#pragma unroll
        for (int ck = 0; ck < 8; ++ck) {
          f32x4 a = {0.f, 0.f, 0.f, 0.f};
#pragma unroll
          for (int kt = 0; kt < 2; ++kt)
            a = MFMA16(qa[kt], ldf(&ks[((hf * 8 + ck) * 16 + lr) * LK + kt * 32 + lg * 8]), a);
          sa[ck] = a;
        }
      }
      // local softmax stats over this half's 128 keys
#pragma unroll
      for (int r = 0; r < 4; ++r) {
        float m = sa[0][r];
#pragma unroll
        for (int ck = 1; ck < 8; ++ck) m = fmaxf(m, sa[ck][r]);
        m = fmaxf(m, __shfl_xor(m, 1));
        m = fmaxf(m, __shfl_xor(m, 2));
        m = fmaxf(m, __shfl_xor(m, 4));
        m = fmaxf(m, __shfl_xor(m, 8));
        float s = 0.f;
#pragma unroll
        for (int ck = 0; ck < 8; ++ck) {
          float e = __expf(sa[ck][r] - m);
          sa[ck][r] = e;
          s += e;
        }
        s += __shfl_xor(s, 1);
        s += __shfl_xor(s, 2);
        s += __shfl_xor(s, 4);
        s += __shfl_xor(s, 8);
        if (lr == 0) sm[g * 16 + lg * 4 + r][hf] = make_float2(m, s);
      }
      __syncthreads();  // both halves' stats ready

      float fac[4];
#pragma unroll
      for (int r = 0; r < 4; ++r) {
        const float2 A = sm[g * 16 + lg * 4 + r][0];
        const float2 B = sm[g * 16 + lg * 4 + r][1];
        const float m = fmaxf(A.x, B.x);
        const float S = A.y * __expf(A.x - m) + B.y * __expf(B.x - m);
        const float myM = hf ? B.x : A.x;
        fac[r] = __expf(myM - m) / S;
      }
#pragma unroll
      for (int ck = 0; ck < 8; ++ck)
#pragma unroll
        for (int r = 0; r < 4; ++r)
          Ps[(g * 16 + lg * 4 + r) * LT + (hf * 8 + ck) * 16 + lr] = f2b(sa[ck][r] * fac[r]);
      __syncthreads();  // full P rows ready

      // R = P @ V  (wave: 16 q-rows, its 2 e-col tiles) -> stored transposed
      {
        bf16x8 pa[8];
#pragma unroll
        for (int kt = 0; kt < 8; ++kt)
          pa[kt] = ldf(&Ps[(g * 16 + lr) * LT + kt * 32 + lg * 8]);
#pragma unroll
        for (int c = 0; c < 2; ++c) {
          const int e = (hf * 2 + c) * 16 + lr;
          f32x4 a = {0.f, 0.f, 0.f, 0.f};
#pragma unroll
          for (int kt = 0; kt < 8; ++kt)
            a = MFMA16(pa[kt], ldf(&vsT[e * LT + kt * 32 + lg * 8]), a);
#pragma unroll
          for (int r = 0; r < 4; ++r)
            RsT[e * LK + g * 16 + lg * 4 + r] = f2b(a[r]);
        }
      }
      __syncthreads();  // RsT ready

      // O += V_blk^T @ R_blk  (wave: 16 d-rows = group g, its 2 e-col tiles)
#pragma unroll
      for (int kt = 0; kt < 2; ++kt) {
        bf16x8 va = ldf(&vsT[(g * 16 + lr) * LT + qb * 64 + kt * 32 + lg * 8]);
#pragma unroll
        for (int c = 0; c < 2; ++c)
          oacc[c] = MFMA16(va, ldf(&RsT[((hf * 2 + c) * 16 + lr) * LK + kt * 32 + lg * 8]), oacc[c]);
      }
      __syncthreads();  // O reads done; next qb may rewrite U/qs/RsT
    }

    // publish this head's O slice
#pragma unroll
    for (int c = 0; c < 2; ++c)
#pragma unroll
      for (int r = 0; r < 4; ++r)
        Os[(g * 16 + lg * 4 + r) * LT + h * 64 + (hf * 2 + c) * 16 + lr] = f2b(oacc[c][r]);
  }

  __syncthreads();  // Os complete

  // ---------------- epilogue (waves 0-3): F = Os @ Wfc, double LayerNorm ----------------
  if (w < 4) {
    bf16x8 oa[8];
#pragma unroll
    for (int kt = 0; kt < 8; ++kt)
      oa[kt] = ldf(&Os[(w * 16 + lr) * LT + kt * 32 + lg * 8]);
    f32x4 fa[4];
#pragma unroll
    for (int ct = 0; ct < 4; ++ct) {
      f32x4 a = {0.f, 0.f, 0.f, 0.f};
#pragma unroll
      for (int kt = 0; kt < 8; ++kt)
        a = MFMA16(oa[kt], wfrag(Wfc, 64, kt * 32 + lg * 8, ct * 16 + lr), a);
      fa[ct] = a;
    }

    float g1v[4], b1v[4], g2v[4], b2v[4];
#pragma unroll
    for (int ct = 0; ct < 4; ++ct) {
      g1v[ct] = ln1g[ct * 16 + lr];
      b1v[ct] = ln1b[ct * 16 + lr];
      g2v[ct] = ln2g[ct * 16 + lr];
      b2v[ct] = ln2b[ct * 16 + lr];
    }
    const int bb = cb & 31;   // graph index
    const int ch = cb >> 5;   // channel index
    float* const obase = out + (size_t)(bb * 8 + ch) * 64 * 64;
#pragma unroll
    for (int r = 0; r < 4; ++r) {
      const int row = w * 16 + lg * 4 + r;
      float x0 = fa[0][r], x1 = fa[1][r], x2 = fa[2][r], x3 = fa[3][r];
      float mu = x0 + x1 + x2 + x3;
      mu += __shfl_xor(mu, 1); mu += __shfl_xor(mu, 2);
      mu += __shfl_xor(mu, 4); mu += __shfl_xor(mu, 8);
      mu *= 0.015625f;
      float d0 = x0 - mu, d1 = x1 - mu, d2 = x2 - mu, d3 = x3 - mu;
      float vr = d0*d0 + d1*d1 + d2*d2 + d3*d3;
      vr += __shfl_xor(vr, 1); vr += __shfl_xor(vr, 2);
      vr += __shfl_xor(vr, 4); vr += __shfl_xor(vr, 8);
      const float is1 = rsqrtf(vr * 0.015625f + 1e-6f);
      float y0 = d0*is1*g1v[0] + b1v[0];
      float y1 = d1*is1*g1v[1] + b1v[1];
      float y2 = d2*is1*g1v[2] + b1v[2];
      float y3 = d3*is1*g1v[3] + b1v[3];
      float mu2 = y0 + y1 + y2 + y3;
      mu2 += __shfl_xor(mu2, 1); mu2 += __shfl_xor(mu2, 2);
      mu2 += __shfl_xor(mu2, 4); mu2 += __shfl_xor(mu2, 8);
      mu2 *= 0.015625f;
      float e0 = y0-mu2, e1 = y1-mu2, e2 = y2-mu2, e3 = y3-mu2;
      float v2 = e0*e0 + e1*e1 + e2*e2 + e3*e3;
      v2 += __shfl_xor(v2, 1); v2 += __shfl_xor(v2, 2);
      v2 += __shfl_xor(v2, 4); v2 += __shfl_xor(v2, 8);
      const float is2 = rsqrtf(v2 * 0.015625f + 1e-6f);
      float* const op = obase + (size_t)row * 64;
      op[ 0 + lr] = e0*is2*g2v[0] + b2v[0];
      op[16 + lr] = e1*is2*g2v[1] + b2v[1];
      op[32 + lr] = e2*is2*g2v[2] + b2v[2];
      op[48 + lr] = e3*is2*g2v[3] + b2v[3];
    }
  }
}

extern "C" void kernel_launch(void* const* d_in, const int* in_sizes, int n_in,
                              void* d_out, int out_size, void* d_ws, size_t ws_size,
                              hipStream_t stream) {
  const float* gnn = (const float*)d_in[0];
  const float* Wq  = (const float*)d_in[1];
  const float* Wk  = (const float*)d_in[2];
  const float* Wv  = (const float*)d_in[3];
  const float* Wfc = (const float*)d_in[4];
  const float* l1g = (const float*)d_in[5];
  const float* l1b = (const float*)d_in[6];
  const float* l2g = (const float*)d_in[7];
  const float* l2b = (const float*)d_in[8];
  (void)in_sizes; (void)n_in; (void)d_ws; (void)ws_size; (void)out_size;
  vlrgat_kernel<<<dim3(256), dim3(512), 0, stream>>>(
      gnn, Wq, Wk, Wv, Wfc, l1g, l1b, l2g, l2b, (float*)d_out);
}